// Round 6
// baseline (1149.526 us; speedup 1.0000x reference)
//
#include <hip/hip_runtime.h>

#define NN 4096
#define EE 131072
#define FFD 2048

typedef float f32x4 __attribute__((ext_vector_type(4)));
typedef __bf16 bf16x8 __attribute__((ext_vector_type(8)));
typedef unsigned short u16;
typedef u16 u16x8 __attribute__((ext_vector_type(8)));

__device__ __forceinline__ u16 f2bf(float f) {
    unsigned u = __builtin_bit_cast(unsigned, f);
    return (u16)((u + 0x7FFFu + ((u >> 16) & 1u)) >> 16);
}

// ---------------- edge dtype detection (int64 vs int32) ----------------
__global__ void k_detect(const int* __restrict__ ei, int* __restrict__ flag) {
    int v = ei[2 * threadIdx.x + 1];
    unsigned long long any = __ballot(v != 0);
    if (threadIdx.x == 0) *flag = (any == 0ULL) ? 1 : 0;   // 1 => int64
}
__device__ __forceinline__ int ldedge(const int* ei, int idx, int is64) {
    return is64 ? ei[2 * idx] : ei[idx];
}

// ---------------- GCN (factored: dinv pre/post, validated R2==R3==R4) ----------------
__global__ void k_deg(const int* __restrict__ ei, const int* __restrict__ flag,
                      float* __restrict__ deg) {
    int e = blockIdx.x * 256 + threadIdx.x;
    if (e >= EE) return;
    atomicAdd(&deg[ldedge(ei, EE + e, *flag)], 1.0f);
}
__global__ void k_dinv(const float* __restrict__ deg, float* __restrict__ dinv) {
    int n = blockIdx.x * 256 + threadIdx.x;
    if (n < NN) dinv[n] = rsqrtf(deg[n] + 1.0f);   // +1 self-loop
}

// ms[n,:] = dinv[n] * (h[n,:] @ W)   (dout = 128): 2 nodes / 256-thread block
__global__ __launch_bounds__(256) void k_gcn_mm128(const float* __restrict__ h,
        const float* __restrict__ W, const float* __restrict__ dinv, float* __restrict__ ms) {
    __shared__ float hr[2][128];
    int t = threadIdx.x, n0 = blockIdx.x * 2, r = t >> 7, e = t & 127;
    hr[r][e] = h[(size_t)(n0 + r) * 128 + e];
    __syncthreads();
    float a = 0.f;
    #pragma unroll 8
    for (int c = 0; c < 128; ++c) a += hr[r][c] * W[c * 128 + e];
    ms[(size_t)(n0 + r) * 128 + e] = a * dinv[n0 + r];
}
// dout = 32, 8 nodes per block
__global__ __launch_bounds__(256) void k_gcn_mm32(const float* __restrict__ h,
        const float* __restrict__ W, const float* __restrict__ dinv, float* __restrict__ ms) {
    __shared__ float hr[8][128];
    int t = threadIdx.x, n0 = blockIdx.x * 8;
    for (int k2 = 0; k2 < 4; ++k2) {
        int idx = k2 * 256 + t;
        hr[idx >> 7][idx & 127] = h[(size_t)n0 * 128 + idx];
    }
    __syncthreads();
    int r = t >> 5, e = t & 31;
    float a = 0.f;
    #pragma unroll 8
    for (int c = 0; c < 128; ++c) a += hr[r][c] * W[c * 32 + e];
    ms[(size_t)(n0 + r) * 32 + e] = a * dinv[n0 + r];
}
// agg[dst,:] += ms[src,:]  over edges; float4 per thread
__global__ void k_scatter(const int* __restrict__ ei, const int* __restrict__ flag,
                          const float* __restrict__ ms, float* __restrict__ agg,
                          int shift, int dout) {
    int idx = blockIdx.x * 256 + threadIdx.x;
    int e = idx >> shift, q = idx & ((1 << shift) - 1);
    int is64 = *flag;
    int src = ldedge(ei, e, is64), dst = ldedge(ei, EE + e, is64);
    float4 v = ((const float4*)(ms + (size_t)src * dout))[q];
    float* a = agg + (size_t)dst * dout + q * 4;
    atomicAdd(a + 0, v.x); atomicAdd(a + 1, v.y);
    atomicAdd(a + 2, v.z); atomicAdd(a + 3, v.w);
}
// hout = relu(dinv[n]*(agg + ms_self) + b)
__global__ void k_fin(const float* __restrict__ agg, const float* __restrict__ ms,
                      const float* __restrict__ dinv, const float* __restrict__ b,
                      float* __restrict__ hout, int shift, int dmask) {
    int idx = blockIdx.x * 256 + threadIdx.x;
    int n = idx >> shift, d = idx & dmask;
    hout[idx] = fmaxf(dinv[n] * (agg[idx] + ms[idx]) + b[d], 0.f);
}

// ---------------- transformer precompute ----------------
// tc: [0)sq [128)sk [256)sv [384)A [392)B [400)C [408)D [416)Po(8x128) [1440)Pb
__global__ __launch_bounds__(128) void k_prep(const float* __restrict__ Wq, const float* __restrict__ bq,
        const float* __restrict__ Wk, const float* __restrict__ bk,
        const float* __restrict__ Wv, const float* __restrict__ bv,
        const float* __restrict__ Wo, const float* __restrict__ bo, float* __restrict__ tc) {
    __shared__ float s_q[128], s_k[128], s_v[128];
    int t = threadIdx.x;
    float aq = 0, ak = 0, av = 0;
    for (int c = 0; c < 128; ++c) {
        aq += Wq[c * 128 + t]; ak += Wk[c * 128 + t]; av += Wv[c * 128 + t];
    }
    s_q[t] = aq; s_k[t] = ak; s_v[t] = av;
    tc[t] = aq; tc[128 + t] = ak; tc[256 + t] = av;
    __syncthreads();
    float pb = 0;
    for (int d = 0; d < 128; ++d) pb += bv[d] * Wo[d * 128 + t];
    tc[1440 + t] = pb + bo[t];
    for (int hh = 0; hh < 8; ++hh) {
        float p = 0;
        #pragma unroll
        for (int d = hh * 16; d < hh * 16 + 16; ++d) p += s_v[d] * Wo[d * 128 + t];
        tc[416 + hh * 128 + t] = p;
    }
    if (t < 8) {
        float A = 0, B = 0, C = 0, D = 0;
        #pragma unroll
        for (int d = t * 16; d < t * 16 + 16; ++d) {
            A += s_q[d] * s_k[d]; B += s_q[d] * bk[d];
            C += bq[d] * s_k[d];  D += bq[d] * bk[d];
        }
        tc[384 + t] = A; tc[392 + t] = B; tc[400 + t] = C; tc[408 + t] = D;
    }
}

// W1 [128][2048] fp32 -> W1T [2048][128] bf16
__global__ void k_w1t(const float* __restrict__ W1, u16* __restrict__ w1t) {
    int t = blockIdx.x * 256 + threadIdx.x;   // 262144
    int f = t >> 7, c = t & 127;
    w1t[t] = f2bf(W1[c * 2048 + f]);
}
// W2 [2048][128] fp32 -> W2T [128][2048] bf16
__global__ void k_w2t(const float* __restrict__ W2, u16* __restrict__ w2t) {
    int t = blockIdx.x * 256 + threadIdx.x;   // 262144
    int o = t >> 11, f = t & 2047;
    w2t[t] = f2bf(W2[f * 128 + o]);
}

// ---------------- attention (collapsed, validated) + LN1 -> x1 (fp32, in d_out) ----------------
__global__ __launch_bounds__(256) void k_attn(const float* __restrict__ h3, const float* __restrict__ tc,
        const float* __restrict__ g1, const float* __restrict__ b1n, float* __restrict__ x1) {
    __shared__ float sh[32];
    __shared__ float ws_[8][32];
    __shared__ float red[8];
    int n = blockIdx.x, t = threadIdx.x;
    if (t < 32) sh[t] = h3[(size_t)n * 32 + t];
    __syncthreads();
    {   // w[hh,i] = sum_j softmax_j(coef*h_j) * h_j ;  coef = (h_i*A+C)/4
        int hh = t >> 5, i = t & 31;
        float A = tc[384 + hh], C = tc[400 + hh];
        float coef = (sh[i] * A + C) * 0.25f;
        float m = -1e30f;
        #pragma unroll
        for (int j = 0; j < 32; ++j) m = fmaxf(m, coef * sh[j]);
        float s = 0.f, wsum = 0.f;
        #pragma unroll
        for (int j = 0; j < 32; ++j) {
            float e = __expf(coef * sh[j] - m);
            s += e; wsum += e * sh[j];
        }
        ws_[hh][i] = wsum / s;
    }
    __syncthreads();
    int half = t >> 7, e = t & 127, wave = t >> 6, lane = t & 63;
    float pb = tc[1440 + e];
    float po[8];
    #pragma unroll
    for (int hh = 0; hh < 8; ++hh) po[hh] = tc[416 + hh * 128 + e];
    float gg = g1[e], bb = b1n[e];
    for (int ii = 0; ii < 32; ii += 2) {
        int i = ii + half;
        float y = sh[i] + pb;
        #pragma unroll
        for (int hh = 0; hh < 8; ++hh) y += ws_[hh][i] * po[hh];
        float s1 = y, s2 = y * y;
        #pragma unroll
        for (int off = 32; off; off >>= 1) {
            s1 += __shfl_down(s1, off); s2 += __shfl_down(s2, off);
        }
        if (lane == 0) { red[wave * 2] = s1; red[wave * 2 + 1] = s2; }
        __syncthreads();
        float t1 = red[half * 4 + 0] + red[half * 4 + 2];
        float t2 = red[half * 4 + 1] + red[half * 4 + 3];
        float mu = t1 * (1.f / 128.f);
        float var = t2 * (1.f / 128.f) - mu * mu;
        float rs = rsqrtf(var + 1e-5f);
        x1[((size_t)n * 32 + i) * 128 + e] = (y - mu) * rs * gg + bb;
        __syncthreads();
    }
}

// ---------------- fused FFN + residual + LN2 (bf16 MFMA), in-place on d_out ----------------
__global__ __launch_bounds__(256) void k_ffn(const float* x1f, const u16* __restrict__ w1t,
        const u16* __restrict__ w2t, const float* __restrict__ b1, const float* __restrict__ b2,
        const float* __restrict__ g2, const float* __restrict__ bt2, float* out) {
    __shared__ u16 x1s[128 * 128];      // bf16, swizzled: byte ^= (row&7)<<4
    __shared__ u16 hid[4][32 * 64];     // per-wave hidden scratch, swizzled
    int t = threadIdx.x, wave = t >> 6, lane = t & 63;
    int g = lane >> 4, li = lane & 15;
    size_t rowbase = (size_t)blockIdx.x * 128;

    // stage x1 tile (128 rows x 128 ch), fp32 -> bf16 swizzled LDS
    #pragma unroll
    for (int it = 0; it < 8; ++it) {
        int idx = (it * 256 + t) * 8;
        int r = idx >> 7, c = idx & 127;
        const float* src = x1f + (rowbase + r) * 128 + c;
        float4 v0 = *(const float4*)(src);
        float4 v1 = *(const float4*)(src + 4);
        u16x8 pv;
        pv[0] = f2bf(v0.x); pv[1] = f2bf(v0.y); pv[2] = f2bf(v0.z); pv[3] = f2bf(v0.w);
        pv[4] = f2bf(v1.x); pv[5] = f2bf(v1.y); pv[6] = f2bf(v1.z); pv[7] = f2bf(v1.w);
        int bo_ = (r * 256 + c * 2) ^ ((r & 7) << 4);
        *(u16x8*)((char*)x1s + bo_) = pv;
    }
    __syncthreads();

    // X1 A-fragments: row = wave*32 + rf*16 + li ; k = ks*32 + g*8 + j
    bf16x8 af[2][4];
    #pragma unroll
    for (int rf = 0; rf < 2; ++rf)
    #pragma unroll
    for (int ks = 0; ks < 4; ++ks) {
        int r = wave * 32 + rf * 16 + li;
        int bo_ = (r * 256 + (ks * 32 + g * 8) * 2) ^ ((r & 7) << 4);
        af[rf][ks] = *(const bf16x8*)((const char*)x1s + bo_);
    }

    f32x4 acc2[2][8];
    #pragma unroll
    for (int a = 0; a < 2; ++a)
    #pragma unroll
    for (int b = 0; b < 8; ++b) acc2[a][b] = (f32x4){0.f, 0.f, 0.f, 0.f};

    u16* hw = &hid[wave][0];
    for (int F = 0; F < FFD; F += 64) {
        f32x4 acc1[2][4];
        #pragma unroll
        for (int a = 0; a < 2; ++a)
        #pragma unroll
        for (int b = 0; b < 4; ++b) acc1[a][b] = (f32x4){0.f, 0.f, 0.f, 0.f};
        #pragma unroll
        for (int ks = 0; ks < 4; ++ks) {
            #pragma unroll
            for (int cf = 0; cf < 4; ++cf) {
                bf16x8 bfrag = *(const bf16x8*)(w1t + (size_t)(F + cf * 16 + li) * 128 + ks * 32 + g * 8);
                acc1[0][cf] = __builtin_amdgcn_mfma_f32_16x16x32_bf16(af[0][ks], bfrag, acc1[0][cf], 0, 0, 0);
                acc1[1][cf] = __builtin_amdgcn_mfma_f32_16x16x32_bf16(af[1][ks], bfrag, acc1[1][cf], 0, 0, 0);
            }
        }
        // bias + relu -> hid (bf16, C-layout scatter)
        #pragma unroll
        for (int cf = 0; cf < 4; ++cf) {
            float bias = b1[F + cf * 16 + li];
            #pragma unroll
            for (int rf = 0; rf < 2; ++rf)
            #pragma unroll
            for (int r = 0; r < 4; ++r) {
                float hv = fmaxf(acc1[rf][cf][r] + bias, 0.f);
                int row = rf * 16 + g * 4 + r;
                int bo_ = (row * 128 + (cf * 16 + li) * 2) ^ ((row & 7) << 4);
                *(u16*)((char*)hw + bo_) = f2bf(hv);
            }
        }
        // matmul2: acc2 += hid @ W2T-chunk   (per-wave LDS, no barrier needed)
        #pragma unroll
        for (int ks2 = 0; ks2 < 2; ++ks2) {
            bf16x8 a2[2];
            #pragma unroll
            for (int rf = 0; rf < 2; ++rf) {
                int row = rf * 16 + li;
                int bo_ = (row * 128 + (ks2 * 32 + g * 8) * 2) ^ ((row & 7) << 4);
                a2[rf] = *(const bf16x8*)((const char*)hw + bo_);
            }
            #pragma unroll
            for (int cf2 = 0; cf2 < 8; ++cf2) {
                bf16x8 bfrag = *(const bf16x8*)(w2t + (size_t)(cf2 * 16 + li) * 2048 + F + ks2 * 32 + g * 8);
                acc2[0][cf2] = __builtin_amdgcn_mfma_f32_16x16x32_bf16(a2[0], bfrag, acc2[0][cf2], 0, 0, 0);
                acc2[1][cf2] = __builtin_amdgcn_mfma_f32_16x16x32_bf16(a2[1], bfrag, acc2[1][cf2], 0, 0, 0);
            }
        }
    }

    // epilogue: y = x1(fp32, re-read own rows) + f + b2 ; out = LN2(y); in-place safe
    #pragma unroll
    for (int rf = 0; rf < 2; ++rf)
    #pragma unroll
    for (int r = 0; r < 4; ++r) {
        int lrow = wave * 32 + rf * 16 + g * 4 + r;
        size_t grow = rowbase + lrow;
        float vals[8], s1 = 0.f, s2 = 0.f;
        #pragma unroll
        for (int cf2 = 0; cf2 < 8; ++cf2) {
            int col = cf2 * 16 + li;
            float xv = x1f[grow * 128 + col];           // own address, read-before-write
            float y = xv + acc2[rf][cf2][r] + b2[col];
            vals[cf2] = y; s1 += y; s2 += y * y;
        }
        #pragma unroll
        for (int m = 1; m < 16; m <<= 1) {
            s1 += __shfl_xor(s1, m); s2 += __shfl_xor(s2, m);
        }
        float mu = s1 * (1.f / 128.f);
        float var = s2 * (1.f / 128.f) - mu * mu;
        float rs = rsqrtf(var + 1e-5f);
        #pragma unroll
        for (int cf2 = 0; cf2 < 8; ++cf2) {
            int col = cf2 * 16 + li;
            out[grow * 128 + col] = (vals[cf2] - mu) * rs * g2[col] + bt2[col];
        }
    }
}

// ---------------- launch ----------------
extern "C" void kernel_launch(void* const* d_in, const int* in_sizes, int n_in,
                              void* d_out, int out_size, void* d_ws, size_t ws_size,
                              hipStream_t stream) {
    const float* x   = (const float*)d_in[0];
    const int*   ei  = (const int*)d_in[1];
    const float *Wg1 = (const float*)d_in[2],  *bg1 = (const float*)d_in[3];
    const float *Wg2 = (const float*)d_in[4],  *bg2 = (const float*)d_in[5];
    const float *Wg3 = (const float*)d_in[6],  *bg3 = (const float*)d_in[7];
    const float *Wq  = (const float*)d_in[8],  *bq  = (const float*)d_in[9];
    const float *Wk  = (const float*)d_in[10], *bk  = (const float*)d_in[11];
    const float *Wv  = (const float*)d_in[12], *bv  = (const float*)d_in[13];
    const float *Wo  = (const float*)d_in[14], *bo  = (const float*)d_in[15];
    const float *g1  = (const float*)d_in[16], *b1n = (const float*)d_in[17];
    const float *W1  = (const float*)d_in[18], *b1  = (const float*)d_in[19];
    const float *W2  = (const float*)d_in[20], *b2  = (const float*)d_in[21];
    const float *g2  = (const float*)d_in[22], *bt2 = (const float*)d_in[23];

    char* ws = (char*)d_ws;
    int*   flag = (int*)(ws + 0);
    float* deg  = (float*)(ws + 4096);
    float* dinv = (float*)(ws + 20480);
    float* ms   = (float*)(ws + 36864);
    float* agg  = (float*)(ws + 2134016);
    float* hA   = (float*)(ws + 4231168);   // h1, later h3
    float* hB   = (float*)(ws + 6328320);   // h2
    float* tc   = (float*)(ws + 8425472);
    u16*   w1t  = (u16*)(ws + 8433664);
    u16*   w2t  = (u16*)(ws + 8957952);
    float* x1   = (float*)d_out;            // fp32 x1 staged in d_out; FFN in-place
    float* out  = (float*)d_out;

    k_detect<<<1, 64, 0, stream>>>(ei, flag);
    hipMemsetAsync(deg, 0, 16384, stream);
    k_deg<<<512, 256, 0, stream>>>(ei, flag, deg);
    k_dinv<<<16, 256, 0, stream>>>(deg, dinv);

    // GCN layer 1
    k_gcn_mm128<<<2048, 256, 0, stream>>>(x, Wg1, dinv, ms);
    hipMemsetAsync(agg, 0, 2097152, stream);
    k_scatter<<<16384, 256, 0, stream>>>(ei, flag, ms, agg, 5, 128);
    k_fin<<<2048, 256, 0, stream>>>(agg, ms, dinv, bg1, hA, 7, 127);
    // GCN layer 2
    k_gcn_mm128<<<2048, 256, 0, stream>>>(hA, Wg2, dinv, ms);
    hipMemsetAsync(agg, 0, 2097152, stream);
    k_scatter<<<16384, 256, 0, stream>>>(ei, flag, ms, agg, 5, 128);
    k_fin<<<2048, 256, 0, stream>>>(agg, ms, dinv, bg2, hB, 7, 127);
    // GCN layer 3
    k_gcn_mm32<<<512, 256, 0, stream>>>(hB, Wg3, dinv, ms);
    hipMemsetAsync(agg, 0, 524288, stream);
    k_scatter<<<4096, 256, 0, stream>>>(ei, flag, ms, agg, 3, 32);
    k_fin<<<512, 256, 0, stream>>>(agg, ms, dinv, bg3, hA, 5, 31);

    // transformer precompute
    k_prep<<<1, 128, 0, stream>>>(Wq, bq, Wk, bk, Wv, bv, Wo, bo, tc);
    k_w1t<<<1024, 256, 0, stream>>>(W1, w1t);
    k_w2t<<<1024, 256, 0, stream>>>(W2, w2t);

    // attention + LN1 -> x1 (fp32, into d_out)
    k_attn<<<4096, 256, 0, stream>>>(hA, tc, g1, b1n, x1);

    // FFN + residual + LN2 -> out (fp32, in-place on d_out)
    k_ffn<<<1024, 256, 0, stream>>>(x1, w1t, w2t, b1, b2, g2, bt2, out);
}

// Round 8
// 718.402 us; speedup vs baseline: 1.6001x; 1.6001x over previous
//
#include <hip/hip_runtime.h>

#define NN 4096
#define EE 131072
#define FFD 2048

typedef float f32x4 __attribute__((ext_vector_type(4)));
typedef __bf16 bf16x8 __attribute__((ext_vector_type(8)));
typedef unsigned int u32;
typedef u32 u32x4 __attribute__((ext_vector_type(4)));
typedef unsigned short u16;

__device__ __forceinline__ u16 f2bf(float f) {       // explicit RNE — do NOT use cvt_pk (biased, R7 lesson)
    unsigned u = __builtin_bit_cast(unsigned, f);
    return (u16)((u + 0x7FFFu + ((u >> 16) & 1u)) >> 16);
}
__device__ __forceinline__ u32 pk2bf(float lo, float hi) {
    return (u32)f2bf(lo) | ((u32)f2bf(hi) << 16);
}

// ---------------- edge dtype detection (int64 vs int32) ----------------
__global__ void k_detect(const int* __restrict__ ei, int* __restrict__ flag) {
    int v = ei[2 * threadIdx.x + 1];
    unsigned long long any = __ballot(v != 0);
    if (threadIdx.x == 0) *flag = (any == 0ULL) ? 1 : 0;   // 1 => int64
}
__device__ __forceinline__ int ldedge(const int* ei, int idx, int is64) {
    return is64 ? ei[2 * idx] : ei[idx];
}

// ---------------- GCN: counting-sort by dst, then gather ----------------
__global__ void k_degi(const int* __restrict__ ei, const int* __restrict__ flag,
                       int* __restrict__ cnt) {
    int e = blockIdx.x * 256 + threadIdx.x;
    if (e >= EE) return;
    atomicAdd(&cnt[ldedge(ei, EE + e, *flag)], 1);
}
__global__ void k_dinv(const int* __restrict__ cnt, float* __restrict__ dinv) {
    int n = blockIdx.x * 256 + threadIdx.x;
    if (n < NN) dinv[n] = rsqrtf((float)cnt[n] + 1.0f);   // +1 self-loop
}
// exclusive prefix over cnt[4096] -> rp[4097], cursor copy
__global__ __launch_bounds__(1024) void k_scan(const int* __restrict__ cnt,
        int* __restrict__ rp, int* __restrict__ cur) {
    __shared__ int tsum[1024];
    int t = threadIdx.x;
    int c0 = cnt[t * 4], c1 = cnt[t * 4 + 1], c2 = cnt[t * 4 + 2], c3 = cnt[t * 4 + 3];
    int s = c0 + c1 + c2 + c3;
    tsum[t] = s;
    __syncthreads();
    for (int off = 1; off < 1024; off <<= 1) {
        int v = (t >= off) ? tsum[t - off] : 0;
        __syncthreads();
        tsum[t] += v;
        __syncthreads();
    }
    int excl = tsum[t] - s;
    int p0 = excl, p1 = excl + c0, p2 = p1 + c1, p3 = p2 + c2;
    rp[t * 4] = p0; rp[t * 4 + 1] = p1; rp[t * 4 + 2] = p2; rp[t * 4 + 3] = p3;
    cur[t * 4] = p0; cur[t * 4 + 1] = p1; cur[t * 4 + 2] = p2; cur[t * 4 + 3] = p3;
    if (t == 1023) rp[4096] = excl + s;
}
__global__ void k_bucket(const int* __restrict__ ei, const int* __restrict__ flag,
                         int* __restrict__ cur, int* __restrict__ es) {
    int e = blockIdx.x * 256 + threadIdx.x;
    if (e >= EE) return;
    int is64 = *flag;
    int s = ldedge(ei, e, is64), d = ldedge(ei, EE + e, is64);
    int pos = atomicAdd(&cur[d], 1);
    es[pos] = s;
}

// ms[n,:] = dinv[n] * (h[n,:] @ W)   (dout = 128): 2 nodes / 256-thread block
__global__ __launch_bounds__(256) void k_gcn_mm128(const float* __restrict__ h,
        const float* __restrict__ W, const float* __restrict__ dinv, float* __restrict__ ms) {
    __shared__ float hr[2][128];
    int t = threadIdx.x, n0 = blockIdx.x * 2, r = t >> 7, e = t & 127;
    hr[r][e] = h[(size_t)(n0 + r) * 128 + e];
    __syncthreads();
    float a = 0.f;
    #pragma unroll 8
    for (int c = 0; c < 128; ++c) a += hr[r][c] * W[c * 128 + e];
    ms[(size_t)(n0 + r) * 128 + e] = a * dinv[n0 + r];
}
// dout = 32, 8 nodes per block
__global__ __launch_bounds__(256) void k_gcn_mm32(const float* __restrict__ h,
        const float* __restrict__ W, const float* __restrict__ dinv, float* __restrict__ ms) {
    __shared__ float hr[8][128];
    int t = threadIdx.x, n0 = blockIdx.x * 8;
    for (int k2 = 0; k2 < 4; ++k2) {
        int idx = k2 * 256 + t;
        hr[idx >> 7][idx & 127] = h[(size_t)n0 * 128 + idx];
    }
    __syncthreads();
    int r = t >> 5, e = t & 31;
    float a = 0.f;
    #pragma unroll 8
    for (int c = 0; c < 128; ++c) a += hr[r][c] * W[c * 32 + e];
    ms[(size_t)(n0 + r) * 32 + e] = a * dinv[n0 + r];
}

// gather (dout=128): one wave per node; h = relu(dinv*(sum + self) + b)
__global__ __launch_bounds__(256) void k_gath128(const int* __restrict__ es,
        const int* __restrict__ rp, const float* __restrict__ ms,
        const float* __restrict__ dinv, const float* __restrict__ b,
        float* __restrict__ hout) {
    int node = blockIdx.x * 4 + (threadIdx.x >> 6), lane = threadIdx.x & 63;
    int st = rp[node], en = rp[node + 1];
    const float2* m2 = (const float2*)ms;
    float ax0 = 0.f, ay0 = 0.f, ax1 = 0.f, ay1 = 0.f;
    int e = st;
    for (; e + 2 <= en; e += 2) {
        int s0 = es[e], s1 = es[e + 1];
        float2 v0 = m2[(size_t)s0 * 64 + lane];
        float2 v1 = m2[(size_t)s1 * 64 + lane];
        ax0 += v0.x; ay0 += v0.y; ax1 += v1.x; ay1 += v1.y;
    }
    if (e < en) {
        float2 v = m2[(size_t)es[e] * 64 + lane];
        ax0 += v.x; ay0 += v.y;
    }
    float dv = dinv[node];
    float2 self = m2[(size_t)node * 64 + lane];
    int c = lane * 2;
    hout[(size_t)node * 128 + c]     = fmaxf(dv * (ax0 + ax1 + self.x) + b[c], 0.f);
    hout[(size_t)node * 128 + c + 1] = fmaxf(dv * (ay0 + ay1 + self.y) + b[c + 1], 0.f);
}
// gather (dout=32): half-wave per node
__global__ __launch_bounds__(256) void k_gath32(const int* __restrict__ es,
        const int* __restrict__ rp, const float* __restrict__ ms,
        const float* __restrict__ dinv, const float* __restrict__ b,
        float* __restrict__ hout) {
    int node = blockIdx.x * 8 + (threadIdx.x >> 5), sl = threadIdx.x & 31;
    int st = rp[node], en = rp[node + 1];
    float a0 = 0.f, a1 = 0.f;
    int e = st;
    for (; e + 2 <= en; e += 2) {
        a0 += ms[(size_t)es[e] * 32 + sl];
        a1 += ms[(size_t)es[e + 1] * 32 + sl];
    }
    if (e < en) a0 += ms[(size_t)es[e] * 32 + sl];
    float dv = dinv[node];
    hout[(size_t)node * 32 + sl] =
        fmaxf(dv * (a0 + a1 + ms[(size_t)node * 32 + sl]) + b[sl], 0.f);
}

// ---------------- transformer precompute ----------------
// tc: [0)sq [128)sk [256)sv [384)A [392)B [400)C [408)D [416)Po(8x128) [1440)Pb
__global__ __launch_bounds__(128) void k_prep(const float* __restrict__ Wq, const float* __restrict__ bq,
        const float* __restrict__ Wk, const float* __restrict__ bk,
        const float* __restrict__ Wv, const float* __restrict__ bv,
        const float* __restrict__ Wo, const float* __restrict__ bo, float* __restrict__ tc) {
    __shared__ float s_q[128], s_k[128], s_v[128];
    int t = threadIdx.x;
    float aq = 0, ak = 0, av = 0;
    for (int c = 0; c < 128; ++c) {
        aq += Wq[c * 128 + t]; ak += Wk[c * 128 + t]; av += Wv[c * 128 + t];
    }
    s_q[t] = aq; s_k[t] = ak; s_v[t] = av;
    tc[t] = aq; tc[128 + t] = ak; tc[256 + t] = av;
    __syncthreads();
    float pb = 0;
    for (int d = 0; d < 128; ++d) pb += bv[d] * Wo[d * 128 + t];
    tc[1440 + t] = pb + bo[t];
    for (int hh = 0; hh < 8; ++hh) {
        float p = 0;
        #pragma unroll
        for (int d = hh * 16; d < hh * 16 + 16; ++d) p += s_v[d] * Wo[d * 128 + t];
        tc[416 + hh * 128 + t] = p;
    }
    if (t < 8) {
        float A = 0, B = 0, C = 0, D = 0;
        #pragma unroll
        for (int d = t * 16; d < t * 16 + 16; ++d) {
            A += s_q[d] * s_k[d]; B += s_q[d] * bk[d];
            C += bq[d] * s_k[d];  D += bq[d] * bk[d];
        }
        tc[384 + t] = A; tc[392 + t] = B; tc[400 + t] = C; tc[408 + t] = D;
    }
}

// W1 [128][2048] fp32 -> W1T [2048][128] bf16
__global__ void k_w1t(const float* __restrict__ W1, u16* __restrict__ w1t) {
    int t = blockIdx.x * 256 + threadIdx.x;
    int f = t >> 7, c = t & 127;
    w1t[t] = f2bf(W1[c * 2048 + f]);
}
// W2 [2048][128] fp32 -> W2T [128][2048] bf16
__global__ void k_w2t(const float* __restrict__ W2, u16* __restrict__ w2t) {
    int t = blockIdx.x * 256 + threadIdx.x;
    int o = t >> 11, f = t & 2047;
    w2t[t] = f2bf(W2[f * 128 + o]);
}

// ---------------- attention (collapsed) + LN1 -> x1 (fp32, in d_out) ----------------
__global__ __launch_bounds__(256) void k_attn(const float* __restrict__ h3, const float* __restrict__ tc,
        const float* __restrict__ g1, const float* __restrict__ b1n, float* __restrict__ x1) {
    __shared__ float sh[32];
    __shared__ float ws_[8][32];
    int n = blockIdx.x, t = threadIdx.x;
    if (t < 32) sh[t] = h3[(size_t)n * 32 + t];
    __syncthreads();
    {   // w[hh,i] = sum_j softmax_j(coef*h_j) * h_j ;  coef = (h_i*A+C)/4
        int hh = t >> 5, i = t & 31;
        float A = tc[384 + hh], C = tc[400 + hh];
        float coef = (sh[i] * A + C) * 0.25f;
        float m = -1e30f;
        #pragma unroll
        for (int j = 0; j < 32; ++j) m = fmaxf(m, coef * sh[j]);
        float s = 0.f, wsum = 0.f;
        #pragma unroll
        for (int j = 0; j < 32; ++j) {
            float e = __expf(coef * sh[j] - m);
            s += e; wsum += e * sh[j];
        }
        ws_[hh][i] = wsum / s;
    }
    __syncthreads();
    int wave = t >> 6, lane = t & 63;
    float pb0 = tc[1440 + lane], pb1 = tc[1440 + lane + 64];
    float po0[8], po1[8];
    #pragma unroll
    for (int hh = 0; hh < 8; ++hh) {
        po0[hh] = tc[416 + hh * 128 + lane];
        po1[hh] = tc[416 + hh * 128 + lane + 64];
    }
    float ga = g1[lane], gb = g1[lane + 64], ba = b1n[lane], bb = b1n[lane + 64];
    for (int i = wave; i < 32; i += 4) {
        float y0 = sh[i] + pb0, y1 = sh[i] + pb1;
        #pragma unroll
        for (int hh = 0; hh < 8; ++hh) {
            float w = ws_[hh][i];
            y0 += w * po0[hh]; y1 += w * po1[hh];
        }
        float s1 = y0 + y1, s2 = y0 * y0 + y1 * y1;
        #pragma unroll
        for (int off = 1; off < 64; off <<= 1) {
            s1 += __shfl_xor(s1, off); s2 += __shfl_xor(s2, off);
        }
        float mu = s1 * (1.f / 128.f);
        float var = s2 * (1.f / 128.f) - mu * mu;
        float rs = rsqrtf(var + 1e-5f);
        size_t base = ((size_t)n * 32 + i) * 128;
        x1[base + lane]      = (y0 - mu) * rs * ga + ba;
        x1[base + lane + 64] = (y1 - mu) * rs * gb + bb;
    }
}

// ---------------- fused FFN + residual + LN2 (bf16 MFMA v2), in-place on d_out ----------------
// Swapped operands: mm1 D = W1frag x X1frag -> lane holds 4 consecutive f (pack+b64 write);
// mm2 D' = W2frag x HIDfrag -> lane holds 4 consecutive out-cols (float4 epilogue).
__global__ __launch_bounds__(256, 3) void k_ffn(const float* x1f, const u16* __restrict__ w1t,
        const u16* __restrict__ w2t, const float* __restrict__ b1, const float* __restrict__ b2,
        const float* __restrict__ g2, const float* __restrict__ bt2, float* out) {
    __shared__ u16 hid[4][32][64];      // per-wave, swizzled
    int t = threadIdx.x, wave = t >> 6, lane = t & 63;
    int g = lane >> 4, li = lane & 15;
    size_t rowbase = (size_t)blockIdx.x * 128;
    char* hwb = (char*)&hid[wave][0][0];
    int swz = ((li & 7) << 4) | (((li >> 3) & 1) << 3);   // row-dependent XOR (row&15 == li)

    // A(x1) fragments: row = wave*32 + rf*16 + li ; k(c) = ks*32 + g*8 + j
    bf16x8 af[2][4];
    #pragma unroll
    for (int rf = 0; rf < 2; ++rf)
    #pragma unroll
    for (int ks = 0; ks < 4; ++ks) {
        const float* p = x1f + (rowbase + wave * 32 + rf * 16 + li) * 128 + ks * 32 + g * 8;
        float4 v0 = *(const float4*)(p);
        float4 v1 = *(const float4*)(p + 4);
        u32x4 q = { pk2bf(v0.x, v0.y), pk2bf(v0.z, v0.w),
                    pk2bf(v1.x, v1.y), pk2bf(v1.z, v1.w) };
        af[rf][ks] = __builtin_bit_cast(bf16x8, q);
    }

    f32x4 acc2[2][8];
    #pragma unroll
    for (int a = 0; a < 2; ++a)
    #pragma unroll
    for (int b = 0; b < 8; ++b) acc2[a][b] = (f32x4){0.f, 0.f, 0.f, 0.f};

    for (int F = 0; F < FFD; F += 64) {
        // ---- mm1: hidT = W1chunk x X1  (process per cf tile) ----
        #pragma unroll
        for (int cf = 0; cf < 4; ++cf) {
            bf16x8 wf[4];
            #pragma unroll
            for (int ks = 0; ks < 4; ++ks)
                wf[ks] = *(const bf16x8*)(w1t + (size_t)(F + cf * 16 + li) * 128 + ks * 32 + g * 8);
            f32x4 a0 = (f32x4){0.f, 0.f, 0.f, 0.f};
            f32x4 a1 = (f32x4){0.f, 0.f, 0.f, 0.f};
            #pragma unroll
            for (int ks = 0; ks < 4; ++ks) {
                a0 = __builtin_amdgcn_mfma_f32_16x16x32_bf16(wf[ks], af[0][ks], a0, 0, 0, 0);
                a1 = __builtin_amdgcn_mfma_f32_16x16x32_bf16(wf[ks], af[1][ks], a1, 0, 0, 0);
            }
            // bias + relu + pack (RNE) -> hid ; D: f = F+cf*16+g*4+r, xr = rf*16+li
            float4 bb4 = *(const float4*)(b1 + F + cf * 16 + g * 4);
            {
                float h0 = fmaxf(a0[0] + bb4.x, 0.f), h1 = fmaxf(a0[1] + bb4.y, 0.f);
                float h2 = fmaxf(a0[2] + bb4.z, 0.f), h3 = fmaxf(a0[3] + bb4.w, 0.f);
                uint2 pk = { pk2bf(h0, h1), pk2bf(h2, h3) };
                *(uint2*)(hwb + (0 * 16 + li) * 128 + ((cf * 32 + g * 8) ^ swz)) = pk;
            }
            {
                float h0 = fmaxf(a1[0] + bb4.x, 0.f), h1 = fmaxf(a1[1] + bb4.y, 0.f);
                float h2 = fmaxf(a1[2] + bb4.z, 0.f), h3 = fmaxf(a1[3] + bb4.w, 0.f);
                uint2 pk = { pk2bf(h0, h1), pk2bf(h2, h3) };
                *(uint2*)(hwb + (1 * 16 + li) * 128 + ((cf * 32 + g * 8) ^ swz)) = pk;
            }
        }
        // ---- mm2: outT += W2chunk x hidT ----
        bf16x8 hf[2][2];   // [rf][ks2]
        #pragma unroll
        for (int rf = 0; rf < 2; ++rf)
        #pragma unroll
        for (int ks2 = 0; ks2 < 2; ++ks2) {
            int rowoff = (rf * 16 + li) * 128;
            uint2 qa = *(const uint2*)(hwb + rowoff + ((ks2 * 64 + g * 16 + 0) ^ swz));
            uint2 qb = *(const uint2*)(hwb + rowoff + ((ks2 * 64 + g * 16 + 8) ^ swz));
            u32x4 q = { qa.x, qa.y, qb.x, qb.y };
            hf[rf][ks2] = __builtin_bit_cast(bf16x8, q);
        }
        #pragma unroll
        for (int cf2 = 0; cf2 < 8; ++cf2) {
            #pragma unroll
            for (int ks2 = 0; ks2 < 2; ++ks2) {
                bf16x8 wf2 = *(const bf16x8*)(w2t + (size_t)(cf2 * 16 + li) * 2048 + F + ks2 * 32 + g * 8);
                acc2[0][cf2] = __builtin_amdgcn_mfma_f32_16x16x32_bf16(wf2, hf[0][ks2], acc2[0][cf2], 0, 0, 0);
                acc2[1][cf2] = __builtin_amdgcn_mfma_f32_16x16x32_bf16(wf2, hf[1][ks2], acc2[1][cf2], 0, 0, 0);
            }
        }
    }

    // epilogue: lane holds row = wave*32+rf*16+li, cols cf2*16+g*4+r
    #pragma unroll
    for (int rf = 0; rf < 2; ++rf) {
        size_t grow = rowbase + wave * 32 + rf * 16 + li;
        f32x4 vals[8];
        float s1 = 0.f, s2 = 0.f;
        #pragma unroll
        for (int cf2 = 0; cf2 < 8; ++cf2) {
            int col = cf2 * 16 + g * 4;
            float4 xv = *(const float4*)(x1f + grow * 128 + col);
            float4 bv = *(const float4*)(b2 + col);
            f32x4 y;
            y[0] = xv.x + acc2[rf][cf2][0] + bv.x;
            y[1] = xv.y + acc2[rf][cf2][1] + bv.y;
            y[2] = xv.z + acc2[rf][cf2][2] + bv.z;
            y[3] = xv.w + acc2[rf][cf2][3] + bv.w;
            vals[cf2] = y;
            s1 += y[0] + y[1] + y[2] + y[3];
            s2 += y[0]*y[0] + y[1]*y[1] + y[2]*y[2] + y[3]*y[3];
        }
        s1 += __shfl_xor(s1, 16); s1 += __shfl_xor(s1, 32);
        s2 += __shfl_xor(s2, 16); s2 += __shfl_xor(s2, 32);
        float mu = s1 * (1.f / 128.f);
        float var = s2 * (1.f / 128.f) - mu * mu;
        float rs = rsqrtf(var + 1e-5f);
        #pragma unroll
        for (int cf2 = 0; cf2 < 8; ++cf2) {
            int col = cf2 * 16 + g * 4;
            float4 gv = *(const float4*)(g2 + col);
            float4 bt = *(const float4*)(bt2 + col);
            float4 o;
            o.x = (vals[cf2][0] - mu) * rs * gv.x + bt.x;
            o.y = (vals[cf2][1] - mu) * rs * gv.y + bt.y;
            o.z = (vals[cf2][2] - mu) * rs * gv.z + bt.z;
            o.w = (vals[cf2][3] - mu) * rs * gv.w + bt.w;
            *(float4*)(out + grow * 128 + col) = o;
        }
    }
}

// ---------------- launch ----------------
extern "C" void kernel_launch(void* const* d_in, const int* in_sizes, int n_in,
                              void* d_out, int out_size, void* d_ws, size_t ws_size,
                              hipStream_t stream) {
    const float* x   = (const float*)d_in[0];
    const int*   ei  = (const int*)d_in[1];
    const float *Wg1 = (const float*)d_in[2],  *bg1 = (const float*)d_in[3];
    const float *Wg2 = (const float*)d_in[4],  *bg2 = (const float*)d_in[5];
    const float *Wg3 = (const float*)d_in[6],  *bg3 = (const float*)d_in[7];
    const float *Wq  = (const float*)d_in[8],  *bq  = (const float*)d_in[9];
    const float *Wk  = (const float*)d_in[10], *bk  = (const float*)d_in[11];
    const float *Wv  = (const float*)d_in[12], *bv  = (const float*)d_in[13];
    const float *Wo  = (const float*)d_in[14], *bo  = (const float*)d_in[15];
    const float *g1  = (const float*)d_in[16], *b1n = (const float*)d_in[17];
    const float *W1  = (const float*)d_in[18], *b1  = (const float*)d_in[19];
    const float *W2  = (const float*)d_in[20], *b2  = (const float*)d_in[21];
    const float *g2  = (const float*)d_in[22], *bt2 = (const float*)d_in[23];

    char* ws = (char*)d_ws;
    int*   flag = (int*)(ws + 0);
    int*   cnt  = (int*)(ws + 4096);
    int*   rp   = (int*)(ws + 20480);
    int*   cur  = (int*)(ws + 40960);
    float* dinv = (float*)(ws + 57344);
    float* ms   = (float*)(ws + 73728);      // 2 MB
    int*   es   = (int*)(ws + 2170880);      // 512 KB
    float* hA   = (float*)(ws + 2695168);    // 2 MB (h1, later h3)
    float* hB   = (float*)(ws + 4792320);    // 2 MB (h2)
    float* tc   = (float*)(ws + 6889472);
    u16*   w1t  = (u16*)(ws + 6897664);      // 512 KB
    u16*   w2t  = (u16*)(ws + 7421952);      // 512 KB
    float* x1   = (float*)d_out;             // fp32 x1 staged in d_out; FFN in-place
    float* out  = (float*)d_out;

    k_detect<<<1, 64, 0, stream>>>(ei, flag);
    hipMemsetAsync(cnt, 0, 16384, stream);
    k_degi<<<512, 256, 0, stream>>>(ei, flag, cnt);
    k_dinv<<<16, 256, 0, stream>>>(cnt, dinv);
    k_scan<<<1, 1024, 0, stream>>>(cnt, rp, cur);
    k_bucket<<<512, 256, 0, stream>>>(ei, flag, cur, es);

    // GCN layer 1
    k_gcn_mm128<<<2048, 256, 0, stream>>>(x, Wg1, dinv, ms);
    k_gath128<<<1024, 256, 0, stream>>>(es, rp, ms, dinv, bg1, hA);
    // GCN layer 2
    k_gcn_mm128<<<2048, 256, 0, stream>>>(hA, Wg2, dinv, ms);
    k_gath128<<<1024, 256, 0, stream>>>(es, rp, ms, dinv, bg2, hB);
    // GCN layer 3
    k_gcn_mm32<<<512, 256, 0, stream>>>(hB, Wg3, dinv, ms);
    k_gath32<<<512, 256, 0, stream>>>(es, rp, ms, dinv, bg3, hA);

    // transformer precompute
    k_prep<<<1, 128, 0, stream>>>(Wq, bq, Wk, bk, Wv, bv, Wo, bo, tc);
    k_w1t<<<1024, 256, 0, stream>>>(W1, w1t);
    k_w2t<<<1024, 256, 0, stream>>>(W2, w2t);

    // attention + LN1 -> x1 (fp32, into d_out)
    k_attn<<<4096, 256, 0, stream>>>(hA, tc, g1, b1n, x1);

    // FFN + residual + LN2 -> out (fp32, in-place on d_out)
    k_ffn<<<1024, 256, 0, stream>>>(x1, w1t, w2t, b1, b2, g2, bt2, out);
}

// Round 10
// 617.074 us; speedup vs baseline: 1.8629x; 1.1642x over previous
//
#include <hip/hip_runtime.h>

#define NN 4096
#define EE 131072
#define FFD 2048

typedef float f32x4 __attribute__((ext_vector_type(4)));
typedef __bf16 bf16x8 __attribute__((ext_vector_type(8)));
typedef unsigned int u32;
typedef u32 u32x4 __attribute__((ext_vector_type(4)));
typedef unsigned short u16;
typedef u16 u16x8 __attribute__((ext_vector_type(8)));

__device__ __forceinline__ u16 f2bf(float f) {       // explicit RNE
    unsigned u = __builtin_bit_cast(unsigned, f);
    return (u16)((u + 0x7FFFu + ((u >> 16) & 1u)) >> 16);
}
__device__ __forceinline__ float bf2f(u16 h) {
    unsigned u = ((unsigned)h) << 16;
    return __builtin_bit_cast(float, u);
}

// ---------------- edge dtype detection (int64 vs int32) ----------------
__global__ void k_detect(const int* __restrict__ ei, int* __restrict__ flag) {
    int v = ei[2 * threadIdx.x + 1];
    unsigned long long any = __ballot(v != 0);
    if (threadIdx.x == 0) *flag = (any == 0ULL) ? 1 : 0;   // 1 => int64
}
__device__ __forceinline__ int ldedge(const int* ei, int idx, int is64) {
    return is64 ? ei[2 * idx] : ei[idx];
}

// ---------------- GCN: counting-sort by dst, then gather ----------------
__global__ void k_degi(const int* __restrict__ ei, const int* __restrict__ flag,
                       int* __restrict__ cnt) {
    int e = blockIdx.x * 256 + threadIdx.x;
    if (e >= EE) return;
    atomicAdd(&cnt[ldedge(ei, EE + e, *flag)], 1);
}
__global__ void k_dinv(const int* __restrict__ cnt, float* __restrict__ dinv) {
    int n = blockIdx.x * 256 + threadIdx.x;
    if (n < NN) dinv[n] = rsqrtf((float)cnt[n] + 1.0f);   // +1 self-loop
}
__global__ __launch_bounds__(1024) void k_scan(const int* __restrict__ cnt,
        int* __restrict__ rp, int* __restrict__ cur) {
    __shared__ int tsum[1024];
    int t = threadIdx.x;
    int c0 = cnt[t * 4], c1 = cnt[t * 4 + 1], c2 = cnt[t * 4 + 2], c3 = cnt[t * 4 + 3];
    int s = c0 + c1 + c2 + c3;
    tsum[t] = s;
    __syncthreads();
    for (int off = 1; off < 1024; off <<= 1) {
        int v = (t >= off) ? tsum[t - off] : 0;
        __syncthreads();
        tsum[t] += v;
        __syncthreads();
    }
    int excl = tsum[t] - s;
    int p0 = excl, p1 = excl + c0, p2 = p1 + c1, p3 = p2 + c2;
    rp[t * 4] = p0; rp[t * 4 + 1] = p1; rp[t * 4 + 2] = p2; rp[t * 4 + 3] = p3;
    cur[t * 4] = p0; cur[t * 4 + 1] = p1; cur[t * 4 + 2] = p2; cur[t * 4 + 3] = p3;
    if (t == 1023) rp[4096] = excl + s;
}
__global__ void k_bucket(const int* __restrict__ ei, const int* __restrict__ flag,
                         int* __restrict__ cur, int* __restrict__ es) {
    int e = blockIdx.x * 256 + threadIdx.x;
    if (e >= EE) return;
    int is64 = *flag;
    int s = ldedge(ei, e, is64), d = ldedge(ei, EE + e, is64);
    int pos = atomicAdd(&cur[d], 1);
    es[pos] = s;
}

// ms[n,:] = dinv[n] * (h[n,:] @ W)   (dout = 128): 2 nodes / 256-thread block
__global__ __launch_bounds__(256) void k_gcn_mm128(const float* __restrict__ h,
        const float* __restrict__ W, const float* __restrict__ dinv, float* __restrict__ ms) {
    __shared__ float hr[2][128];
    int t = threadIdx.x, n0 = blockIdx.x * 2, r = t >> 7, e = t & 127;
    hr[r][e] = h[(size_t)(n0 + r) * 128 + e];
    __syncthreads();
    float a = 0.f;
    #pragma unroll 8
    for (int c = 0; c < 128; ++c) a += hr[r][c] * W[c * 128 + e];
    ms[(size_t)(n0 + r) * 128 + e] = a * dinv[n0 + r];
}
// dout = 32, 8 nodes per block
__global__ __launch_bounds__(256) void k_gcn_mm32(const float* __restrict__ h,
        const float* __restrict__ W, const float* __restrict__ dinv, float* __restrict__ ms) {
    __shared__ float hr[8][128];
    int t = threadIdx.x, n0 = blockIdx.x * 8;
    for (int k2 = 0; k2 < 4; ++k2) {
        int idx = k2 * 256 + t;
        hr[idx >> 7][idx & 127] = h[(size_t)n0 * 128 + idx];
    }
    __syncthreads();
    int r = t >> 5, e = t & 31;
    float a = 0.f;
    #pragma unroll 8
    for (int c = 0; c < 128; ++c) a += hr[r][c] * W[c * 32 + e];
    ms[(size_t)(n0 + r) * 32 + e] = a * dinv[n0 + r];
}

// gather (dout=128): one wave per node
__global__ __launch_bounds__(256) void k_gath128(const int* __restrict__ es,
        const int* __restrict__ rp, const float* __restrict__ ms,
        const float* __restrict__ dinv, const float* __restrict__ b,
        float* __restrict__ hout) {
    int node = blockIdx.x * 4 + (threadIdx.x >> 6), lane = threadIdx.x & 63;
    int st = rp[node], en = rp[node + 1];
    const float2* m2 = (const float2*)ms;
    float ax0 = 0.f, ay0 = 0.f, ax1 = 0.f, ay1 = 0.f;
    int e = st;
    for (; e + 2 <= en; e += 2) {
        int s0 = es[e], s1 = es[e + 1];
        float2 v0 = m2[(size_t)s0 * 64 + lane];
        float2 v1 = m2[(size_t)s1 * 64 + lane];
        ax0 += v0.x; ay0 += v0.y; ax1 += v1.x; ay1 += v1.y;
    }
    if (e < en) {
        float2 v = m2[(size_t)es[e] * 64 + lane];
        ax0 += v.x; ay0 += v.y;
    }
    float dv = dinv[node];
    float2 self = m2[(size_t)node * 64 + lane];
    int c = lane * 2;
    hout[(size_t)node * 128 + c]     = fmaxf(dv * (ax0 + ax1 + self.x) + b[c], 0.f);
    hout[(size_t)node * 128 + c + 1] = fmaxf(dv * (ay0 + ay1 + self.y) + b[c + 1], 0.f);
}
// gather (dout=32): half-wave per node
__global__ __launch_bounds__(256) void k_gath32(const int* __restrict__ es,
        const int* __restrict__ rp, const float* __restrict__ ms,
        const float* __restrict__ dinv, const float* __restrict__ b,
        float* __restrict__ hout) {
    int node = blockIdx.x * 8 + (threadIdx.x >> 5), sl = threadIdx.x & 31;
    int st = rp[node], en = rp[node + 1];
    float a0 = 0.f, a1 = 0.f;
    int e = st;
    for (; e + 2 <= en; e += 2) {
        a0 += ms[(size_t)es[e] * 32 + sl];
        a1 += ms[(size_t)es[e + 1] * 32 + sl];
    }
    if (e < en) a0 += ms[(size_t)es[e] * 32 + sl];
    float dv = dinv[node];
    hout[(size_t)node * 32 + sl] =
        fmaxf(dv * (a0 + a1 + ms[(size_t)node * 32 + sl]) + b[sl], 0.f);
}

// ---------------- transformer precompute ----------------
// tc: [0)sq [128)sk [256)sv [384)A [392)B [400)C [408)D [416)Po(8x128) [1440)Pb
__global__ __launch_bounds__(128) void k_prep(const float* __restrict__ Wq, const float* __restrict__ bq,
        const float* __restrict__ Wk, const float* __restrict__ bk,
        const float* __restrict__ Wv, const float* __restrict__ bv,
        const float* __restrict__ Wo, const float* __restrict__ bo, float* __restrict__ tc) {
    __shared__ float s_q[128], s_k[128], s_v[128];
    int t = threadIdx.x;
    float aq = 0, ak = 0, av = 0;
    for (int c = 0; c < 128; ++c) {
        aq += Wq[c * 128 + t]; ak += Wk[c * 128 + t]; av += Wv[c * 128 + t];
    }
    s_q[t] = aq; s_k[t] = ak; s_v[t] = av;
    tc[t] = aq; tc[128 + t] = ak; tc[256 + t] = av;
    __syncthreads();
    float pb = 0;
    for (int d = 0; d < 128; ++d) pb += bv[d] * Wo[d * 128 + t];
    tc[1440 + t] = pb + bo[t];
    for (int hh = 0; hh < 8; ++hh) {
        float p = 0;
        #pragma unroll
        for (int d = hh * 16; d < hh * 16 + 16; ++d) p += s_v[d] * Wo[d * 128 + t];
        tc[416 + hh * 128 + t] = p;
    }
    if (t < 8) {
        float A = 0, B = 0, C = 0, D = 0;
        #pragma unroll
        for (int d = t * 16; d < t * 16 + 16; ++d) {
            A += s_q[d] * s_k[d]; B += s_q[d] * bk[d];
            C += bq[d] * s_k[d];  D += bq[d] * bk[d];
        }
        tc[384 + t] = A; tc[392 + t] = B; tc[400 + t] = C; tc[408 + t] = D;
    }
}

// W1 [128][2048] fp32 -> W1T [2048][128] bf16
__global__ void k_w1t(const float* __restrict__ W1, u16* __restrict__ w1t) {
    int t = blockIdx.x * 256 + threadIdx.x;
    int f = t >> 7, c = t & 127;
    w1t[t] = f2bf(W1[c * 2048 + f]);
}
// W2 [2048][128] fp32 -> W2T [128][2048] bf16
__global__ void k_w2t(const float* __restrict__ W2, u16* __restrict__ w2t) {
    int t = blockIdx.x * 256 + threadIdx.x;
    int o = t >> 11, f = t & 2047;
    w2t[t] = f2bf(W2[f * 128 + o]);
}

// ---------------- attention (collapsed) + LN1 -> x1 (fp32, in d_out) ----------------
__global__ __launch_bounds__(256) void k_attn(const float* __restrict__ h3, const float* __restrict__ tc,
        const float* __restrict__ g1, const float* __restrict__ b1n, float* __restrict__ x1) {
    __shared__ float sh[32];
    __shared__ float ws_[8][32];
    int n = blockIdx.x, t = threadIdx.x;
    if (t < 32) sh[t] = h3[(size_t)n * 32 + t];
    __syncthreads();
    {   // w[hh,i] = sum_j softmax_j(coef*h_j) * h_j ;  coef = (h_i*A+C)/4
        int hh = t >> 5, i = t & 31;
        float A = tc[384 + hh], C = tc[400 + hh];
        float coef = (sh[i] * A + C) * 0.25f;
        float m = -1e30f;
        #pragma unroll
        for (int j = 0; j < 32; ++j) m = fmaxf(m, coef * sh[j]);
        float s = 0.f, wsum = 0.f;
        #pragma unroll
        for (int j = 0; j < 32; ++j) {
            float e = __expf(coef * sh[j] - m);
            s += e; wsum += e * sh[j];
        }
        ws_[hh][i] = wsum / s;
    }
    __syncthreads();
    int wave = t >> 6, lane = t & 63;
    float pb0 = tc[1440 + lane], pb1 = tc[1440 + lane + 64];
    float po0[8], po1[8];
    #pragma unroll
    for (int hh = 0; hh < 8; ++hh) {
        po0[hh] = tc[416 + hh * 128 + lane];
        po1[hh] = tc[416 + hh * 128 + lane + 64];
    }
    float ga = g1[lane], gb = g1[lane + 64], ba = b1n[lane], bb = b1n[lane + 64];
    for (int i = wave; i < 32; i += 4) {
        float y0 = sh[i] + pb0, y1 = sh[i] + pb1;
        #pragma unroll
        for (int hh = 0; hh < 8; ++hh) {
            float w = ws_[hh][i];
            y0 += w * po0[hh]; y1 += w * po1[hh];
        }
        float s1 = y0 + y1, s2 = y0 * y0 + y1 * y1;
        #pragma unroll
        for (int off = 1; off < 64; off <<= 1) {
            s1 += __shfl_xor(s1, off); s2 += __shfl_xor(s2, off);
        }
        float mu = s1 * (1.f / 128.f);
        float var = s2 * (1.f / 128.f) - mu * mu;
        float rs = rsqrtf(var + 1e-5f);
        size_t base = ((size_t)n * 32 + i) * 128;
        x1[base + lane]      = (y0 - mu) * rs * ga + ba;
        x1[base + lane + 64] = (y1 - mu) * rs * gb + bb;
    }
}

// ---------------- fused FFN + residual + LN2: R6-validated math + pipelined loads ----------------
// Math identical to R6 (absmax 0.0156): x1 staged bf16 in swizzled LDS; mm1 A=x1,B=W1T;
// hid bf16 per-wave LDS; mm2 A=hid,B=W2T; residual from bf16 LDS.
// Schedule: W2 chunk batch-loaded at step top (hides under mm1); W1 4-frag groups
// ping-pong prefetched one cf ahead + cross-step (hides under MFMAs).

#define LOADW1G(dst, Fb, cfi)                                                    \
    { _Pragma("unroll") for (int ks_ = 0; ks_ < 4; ++ks_)                        \
        dst[ks_] = *(const bf16x8*)(w1t +                                        \
            (size_t)((Fb) + (cfi) * 16 + li) * 128 + ks_ * 32 + g * 8); }

#define LOADW2(dst, Fb)                                                          \
    { _Pragma("unroll") for (int c2_ = 0; c2_ < 8; ++c2_)                        \
      _Pragma("unroll") for (int k2_ = 0; k2_ < 2; ++k2_)                        \
        dst[c2_ * 2 + k2_] = *(const bf16x8*)(w2t +                              \
            (size_t)(c2_ * 16 + li) * 2048 + (Fb) + k2_ * 32 + g * 8); }

// mm1 for one cf group (R6 operand order) + bias/relu/pack to hid
#define MM1G(w1, Fb, cfi)                                                        \
    { f32x4 a0_ = (f32x4){0.f, 0.f, 0.f, 0.f};                                   \
      f32x4 a1_ = (f32x4){0.f, 0.f, 0.f, 0.f};                                   \
      _Pragma("unroll") for (int ks_ = 0; ks_ < 4; ++ks_) {                      \
        a0_ = __builtin_amdgcn_mfma_f32_16x16x32_bf16(af[0][ks_], w1[ks_], a0_, 0, 0, 0); \
        a1_ = __builtin_amdgcn_mfma_f32_16x16x32_bf16(af[1][ks_], w1[ks_], a1_, 0, 0, 0); \
      }                                                                          \
      float bias_ = b1[(Fb) + (cfi) * 16 + li];                                  \
      _Pragma("unroll") for (int r_ = 0; r_ < 4; ++r_) {                         \
        int row0_ = 0 * 16 + g * 4 + r_;                                         \
        int row1_ = 1 * 16 + g * 4 + r_;                                         \
        *(u16*)(hwb + ((row0_ * 128 + ((cfi) * 16 + li) * 2) ^ ((row0_ & 7) << 4))) \
            = f2bf(fmaxf(a0_[r_] + bias_, 0.f));                                 \
        *(u16*)(hwb + ((row1_ * 128 + ((cfi) * 16 + li) * 2) ^ ((row1_ & 7) << 4))) \
            = f2bf(fmaxf(a1_[r_] + bias_, 0.f));                                 \
      } }

#define MM2(w2)                                                                  \
    { _Pragma("unroll") for (int k2_ = 0; k2_ < 2; ++k2_) {                      \
        bf16x8 a2_[2];                                                           \
        _Pragma("unroll") for (int rf_ = 0; rf_ < 2; ++rf_) {                    \
            int row_ = rf_ * 16 + li;                                            \
            a2_[rf_] = *(const bf16x8*)(hwb +                                    \
                ((row_ * 128 + (k2_ * 32 + g * 8) * 2) ^ ((row_ & 7) << 4)));    \
        }                                                                        \
        _Pragma("unroll") for (int c2_ = 0; c2_ < 8; ++c2_) {                    \
            acc2[0][c2_] = __builtin_amdgcn_mfma_f32_16x16x32_bf16(a2_[0],       \
                               w2[c2_ * 2 + k2_], acc2[0][c2_], 0, 0, 0);        \
            acc2[1][c2_] = __builtin_amdgcn_mfma_f32_16x16x32_bf16(a2_[1],       \
                               w2[c2_ * 2 + k2_], acc2[1][c2_], 0, 0, 0);        \
        }                                                                        \
      } }

__global__ __launch_bounds__(256, 2) void k_ffn(const float* x1f, const u16* __restrict__ w1t,
        const u16* __restrict__ w2t, const float* __restrict__ b1, const float* __restrict__ b2,
        const float* __restrict__ g2, const float* __restrict__ bt2, float* out) {
    __shared__ u16 x1s[128 * 128];      // bf16, swizzled: byte ^= (row&7)<<4
    __shared__ u16 hid[4][32 * 64];     // per-wave hidden scratch, swizzled
    int t = threadIdx.x, wave = t >> 6, lane = t & 63;
    int g = lane >> 4, li = lane & 15;
    size_t rowbase = (size_t)blockIdx.x * 128;
    char* hwb = (char*)&hid[wave][0];

    // stage x1 tile fp32 -> bf16 swizzled LDS (R6 layout)
    #pragma unroll
    for (int it = 0; it < 8; ++it) {
        int idx = (it * 256 + t) * 8;
        int r = idx >> 7, c = idx & 127;
        const float* src = x1f + (rowbase + r) * 128 + c;
        float4 v0 = *(const float4*)(src);
        float4 v1 = *(const float4*)(src + 4);
        u16x8 pv;
        pv[0] = f2bf(v0.x); pv[1] = f2bf(v0.y); pv[2] = f2bf(v0.z); pv[3] = f2bf(v0.w);
        pv[4] = f2bf(v1.x); pv[5] = f2bf(v1.y); pv[6] = f2bf(v1.z); pv[7] = f2bf(v1.w);
        int bo_ = (r * 256 + c * 2) ^ ((r & 7) << 4);
        *(u16x8*)((char*)x1s + bo_) = pv;
    }
    __syncthreads();

    // A(x1) fragments (R6): row = wave*32 + rf*16 + li ; k = ks*32 + g*8 + j
    bf16x8 af[2][4];
    #pragma unroll
    for (int rf = 0; rf < 2; ++rf)
    #pragma unroll
    for (int ks = 0; ks < 4; ++ks) {
        int r = wave * 32 + rf * 16 + li;
        int bo_ = (r * 256 + (ks * 32 + g * 8) * 2) ^ ((r & 7) << 4);
        af[rf][ks] = *(const bf16x8*)((const char*)x1s + bo_);
    }

    f32x4 acc2[2][8];
    #pragma unroll
    for (int a = 0; a < 2; ++a)
    #pragma unroll
    for (int b = 0; b < 8; ++b) acc2[a][b] = (f32x4){0.f, 0.f, 0.f, 0.f};

    bf16x8 w1c[4], w1n[4], w2c[16];
    LOADW1G(w1c, 0, 0);
    for (int F = 0; F < FFD; F += 64) {
        LOADW2(w2c, F);                         // in flight during mm1
        LOADW1G(w1n, F, 1);  MM1G(w1c, F, 0);   // prefetch cf+1 under cf's MFMAs
        LOADW1G(w1c, F, 2);  MM1G(w1n, F, 1);
        LOADW1G(w1n, F, 3);  MM1G(w1c, F, 2);
        int Fn = (F + 64 < FFD) ? F + 64 : 0;   // cross-step prefetch (last one unused)
        LOADW1G(w1c, Fn, 0); MM1G(w1n, F, 3);
        MM2(w2c);
    }

    // epilogue (R6): lane holds rows wave*32+rf*16+g*4+r, cols cf2*16+li; residual bf16 LDS
    #pragma unroll
    for (int rf = 0; rf < 2; ++rf)
    #pragma unroll
    for (int r = 0; r < 4; ++r) {
        int lrow = wave * 32 + rf * 16 + g * 4 + r;
        float vals[8], s1 = 0.f, s2 = 0.f;
        #pragma unroll
        for (int cf2 = 0; cf2 < 8; ++cf2) {
            int col = cf2 * 16 + li;
            int bo_ = (lrow * 256 + col * 2) ^ ((lrow & 7) << 4);
            float xv = bf2f(*(const u16*)((const char*)x1s + bo_));
            float y = xv + acc2[rf][cf2][r] + b2[col];
            vals[cf2] = y; s1 += y; s2 += y * y;
        }
        #pragma unroll
        for (int m = 1; m < 16; m <<= 1) {
            s1 += __shfl_xor(s1, m); s2 += __shfl_xor(s2, m);
        }
        float mu = s1 * (1.f / 128.f);
        float var = s2 * (1.f / 128.f) - mu * mu;
        float rs = rsqrtf(var + 1e-5f);
        size_t grow = rowbase + lrow;
        #pragma unroll
        for (int cf2 = 0; cf2 < 8; ++cf2) {
            int col = cf2 * 16 + li;
            out[grow * 128 + col] = (vals[cf2] - mu) * rs * g2[col] + bt2[col];
        }
    }
}

// ---------------- launch ----------------
extern "C" void kernel_launch(void* const* d_in, const int* in_sizes, int n_in,
                              void* d_out, int out_size, void* d_ws, size_t ws_size,
                              hipStream_t stream) {
    const float* x   = (const float*)d_in[0];
    const int*   ei  = (const int*)d_in[1];
    const float *Wg1 = (const float*)d_in[2],  *bg1 = (const float*)d_in[3];
    const float *Wg2 = (const float*)d_in[4],  *bg2 = (const float*)d_in[5];
    const float *Wg3 = (const float*)d_in[6],  *bg3 = (const float*)d_in[7];
    const float *Wq  = (const float*)d_in[8],  *bq  = (const float*)d_in[9];
    const float *Wk  = (const float*)d_in[10], *bk  = (const float*)d_in[11];
    const float *Wv  = (const float*)d_in[12], *bv  = (const float*)d_in[13];
    const float *Wo  = (const float*)d_in[14], *bo  = (const float*)d_in[15];
    const float *g1  = (const float*)d_in[16], *b1n = (const float*)d_in[17];
    const float *W1  = (const float*)d_in[18], *b1  = (const float*)d_in[19];
    const float *W2  = (const float*)d_in[20], *b2  = (const float*)d_in[21];
    const float *g2  = (const float*)d_in[22], *bt2 = (const float*)d_in[23];

    char* ws = (char*)d_ws;
    int*   flag = (int*)(ws + 0);
    int*   cnt  = (int*)(ws + 4096);
    int*   rp   = (int*)(ws + 20480);
    int*   cur  = (int*)(ws + 40960);
    float* dinv = (float*)(ws + 57344);
    float* ms   = (float*)(ws + 73728);      // 2 MB
    int*   es   = (int*)(ws + 2170880);      // 512 KB
    float* hA   = (float*)(ws + 2695168);    // 2 MB (h1, later h3)
    float* hB   = (float*)(ws + 4792320);    // 2 MB (h2)
    float* tc   = (float*)(ws + 6889472);
    u16*   w1t  = (u16*)(ws + 6897664);      // 512 KB
    u16*   w2t  = (u16*)(ws + 7421952);      // 512 KB
    float* x1   = (float*)d_out;             // fp32 x1 staged in d_out; FFN in-place
    float* out  = (float*)d_out;

    k_detect<<<1, 64, 0, stream>>>(ei, flag);
    hipMemsetAsync(cnt, 0, 16384, stream);
    k_degi<<<512, 256, 0, stream>>>(ei, flag, cnt);
    k_dinv<<<16, 256, 0, stream>>>(cnt, dinv);
    k_scan<<<1, 1024, 0, stream>>>(cnt, rp, cur);
    k_bucket<<<512, 256, 0, stream>>>(ei, flag, cur, es);

    // GCN layer 1
    k_gcn_mm128<<<2048, 256, 0, stream>>>(x, Wg1, dinv, ms);
    k_gath128<<<1024, 256, 0, stream>>>(es, rp, ms, dinv, bg1, hA);
    // GCN layer 2
    k_gcn_mm128<<<2048, 256, 0, stream>>>(hA, Wg2, dinv, ms);
    k_gath128<<<1024, 256, 0, stream>>>(es, rp, ms, dinv, bg2, hB);
    // GCN layer 3
    k_gcn_mm32<<<512, 256, 0, stream>>>(hB, Wg3, dinv, ms);
    k_gath32<<<512, 256, 0, stream>>>(es, rp, ms, dinv, bg3, hA);

    // transformer precompute
    k_prep<<<1, 128, 0, stream>>>(Wq, bq, Wk, bk, Wv, bv, Wo, bo, tc);
    k_w1t<<<1024, 256, 0, stream>>>(W1, w1t);
    k_w2t<<<1024, 256, 0, stream>>>(W2, w2t);

    // attention + LN1 -> x1 (fp32, into d_out)
    k_attn<<<4096, 256, 0, stream>>>(hA, tc, g1, b1n, x1);

    // FFN + residual + LN2 -> out (fp32, in-place on d_out)
    k_ffn<<<1024, 256, 0, stream>>>(x1, w1t, w2t, b1, b2, g2, bt2, out);
}

// Round 11
// 306.437 us; speedup vs baseline: 3.7513x; 2.0137x over previous
//
#include <hip/hip_runtime.h>

#define NN 4096
#define EE 131072
#define FFD 2048

typedef float f32x4 __attribute__((ext_vector_type(4)));
typedef __bf16 bf16x8 __attribute__((ext_vector_type(8)));
typedef unsigned int u32;
typedef u32 u32x4 __attribute__((ext_vector_type(4)));
typedef unsigned short u16;
typedef u16 u16x8 __attribute__((ext_vector_type(8)));

__device__ __forceinline__ u16 f2bf(float f) {       // explicit RNE
    unsigned u = __builtin_bit_cast(unsigned, f);
    return (u16)((u + 0x7FFFu + ((u >> 16) & 1u)) >> 16);
}
__device__ __forceinline__ float bf2f(u16 h) {
    unsigned u = ((unsigned)h) << 16;
    return __builtin_bit_cast(float, u);
}
__device__ __forceinline__ u32 pk2bf(float lo, float hi) {
    return (u32)f2bf(lo) | ((u32)f2bf(hi) << 16);
}

#define GLD16(g, l) __builtin_amdgcn_global_load_lds(                            \
    (const __attribute__((address_space(1))) void*)(g),                          \
    (__attribute__((address_space(3))) void*)(l), 16, 0, 0)

// ---------------- edge dtype detection (int64 vs int32) ----------------
__global__ void k_detect(const int* __restrict__ ei, int* __restrict__ flag) {
    int v = ei[2 * threadIdx.x + 1];
    unsigned long long any = __ballot(v != 0);
    if (threadIdx.x == 0) *flag = (any == 0ULL) ? 1 : 0;   // 1 => int64
}
__device__ __forceinline__ int ldedge(const int* ei, int idx, int is64) {
    return is64 ? ei[2 * idx] : ei[idx];
}

// ---------------- GCN: counting-sort by dst, then gather ----------------
__global__ void k_degi(const int* __restrict__ ei, const int* __restrict__ flag,
                       int* __restrict__ cnt) {
    int e = blockIdx.x * 256 + threadIdx.x;
    if (e >= EE) return;
    atomicAdd(&cnt[ldedge(ei, EE + e, *flag)], 1);
}
__global__ void k_dinv(const int* __restrict__ cnt, float* __restrict__ dinv) {
    int n = blockIdx.x * 256 + threadIdx.x;
    if (n < NN) dinv[n] = rsqrtf((float)cnt[n] + 1.0f);   // +1 self-loop
}
__global__ __launch_bounds__(1024) void k_scan(const int* __restrict__ cnt,
        int* __restrict__ rp, int* __restrict__ cur) {
    __shared__ int tsum[1024];
    int t = threadIdx.x;
    int c0 = cnt[t * 4], c1 = cnt[t * 4 + 1], c2 = cnt[t * 4 + 2], c3 = cnt[t * 4 + 3];
    int s = c0 + c1 + c2 + c3;
    tsum[t] = s;
    __syncthreads();
    for (int off = 1; off < 1024; off <<= 1) {
        int v = (t >= off) ? tsum[t - off] : 0;
        __syncthreads();
        tsum[t] += v;
        __syncthreads();
    }
    int excl = tsum[t] - s;
    int p0 = excl, p1 = excl + c0, p2 = p1 + c1, p3 = p2 + c2;
    rp[t * 4] = p0; rp[t * 4 + 1] = p1; rp[t * 4 + 2] = p2; rp[t * 4 + 3] = p3;
    cur[t * 4] = p0; cur[t * 4 + 1] = p1; cur[t * 4 + 2] = p2; cur[t * 4 + 3] = p3;
    if (t == 1023) rp[4096] = excl + s;
}
__global__ void k_bucket(const int* __restrict__ ei, const int* __restrict__ flag,
                         int* __restrict__ cur, int* __restrict__ es) {
    int e = blockIdx.x * 256 + threadIdx.x;
    if (e >= EE) return;
    int is64 = *flag;
    int s = ldedge(ei, e, is64), d = ldedge(ei, EE + e, is64);
    int pos = atomicAdd(&cur[d], 1);
    es[pos] = s;
}

// ms[n,:] = dinv[n] * (h[n,:] @ W)   (dout = 128): 2 nodes / 256-thread block
__global__ __launch_bounds__(256) void k_gcn_mm128(const float* __restrict__ h,
        const float* __restrict__ W, const float* __restrict__ dinv, float* __restrict__ ms) {
    __shared__ float hr[2][128];
    int t = threadIdx.x, n0 = blockIdx.x * 2, r = t >> 7, e = t & 127;
    hr[r][e] = h[(size_t)(n0 + r) * 128 + e];
    __syncthreads();
    float a = 0.f;
    #pragma unroll 8
    for (int c = 0; c < 128; ++c) a += hr[r][c] * W[c * 128 + e];
    ms[(size_t)(n0 + r) * 128 + e] = a * dinv[n0 + r];
}
// dout = 32, 8 nodes per block
__global__ __launch_bounds__(256) void k_gcn_mm32(const float* __restrict__ h,
        const float* __restrict__ W, const float* __restrict__ dinv, float* __restrict__ ms) {
    __shared__ float hr[8][128];
    int t = threadIdx.x, n0 = blockIdx.x * 8;
    for (int k2 = 0; k2 < 4; ++k2) {
        int idx = k2 * 256 + t;
        hr[idx >> 7][idx & 127] = h[(size_t)n0 * 128 + idx];
    }
    __syncthreads();
    int r = t >> 5, e = t & 31;
    float a = 0.f;
    #pragma unroll 8
    for (int c = 0; c < 128; ++c) a += hr[r][c] * W[c * 32 + e];
    ms[(size_t)(n0 + r) * 32 + e] = a * dinv[n0 + r];
}

// gather (dout=128): one wave per node
__global__ __launch_bounds__(256) void k_gath128(const int* __restrict__ es,
        const int* __restrict__ rp, const float* __restrict__ ms,
        const float* __restrict__ dinv, const float* __restrict__ b,
        float* __restrict__ hout) {
    int node = blockIdx.x * 4 + (threadIdx.x >> 6), lane = threadIdx.x & 63;
    int st = rp[node], en = rp[node + 1];
    const float2* m2 = (const float2*)ms;
    float ax0 = 0.f, ay0 = 0.f, ax1 = 0.f, ay1 = 0.f;
    int e = st;
    for (; e + 2 <= en; e += 2) {
        int s0 = es[e], s1 = es[e + 1];
        float2 v0 = m2[(size_t)s0 * 64 + lane];
        float2 v1 = m2[(size_t)s1 * 64 + lane];
        ax0 += v0.x; ay0 += v0.y; ax1 += v1.x; ay1 += v1.y;
    }
    if (e < en) {
        float2 v = m2[(size_t)es[e] * 64 + lane];
        ax0 += v.x; ay0 += v.y;
    }
    float dv = dinv[node];
    float2 self = m2[(size_t)node * 64 + lane];
    int c = lane * 2;
    hout[(size_t)node * 128 + c]     = fmaxf(dv * (ax0 + ax1 + self.x) + b[c], 0.f);
    hout[(size_t)node * 128 + c + 1] = fmaxf(dv * (ay0 + ay1 + self.y) + b[c + 1], 0.f);
}
// gather (dout=32): half-wave per node
__global__ __launch_bounds__(256) void k_gath32(const int* __restrict__ es,
        const int* __restrict__ rp, const float* __restrict__ ms,
        const float* __restrict__ dinv, const float* __restrict__ b,
        float* __restrict__ hout) {
    int node = blockIdx.x * 8 + (threadIdx.x >> 5), sl = threadIdx.x & 31;
    int st = rp[node], en = rp[node + 1];
    float a0 = 0.f, a1 = 0.f;
    int e = st;
    for (; e + 2 <= en; e += 2) {
        a0 += ms[(size_t)es[e] * 32 + sl];
        a1 += ms[(size_t)es[e + 1] * 32 + sl];
    }
    if (e < en) a0 += ms[(size_t)es[e] * 32 + sl];
    float dv = dinv[node];
    hout[(size_t)node * 32 + sl] =
        fmaxf(dv * (a0 + a1 + ms[(size_t)node * 32 + sl]) + b[sl], 0.f);
}

// ---------------- transformer precompute ----------------
// tc: [0)sq [128)sk [256)sv [384)A [392)B [400)C [408)D [416)Po(8x128) [1440)Pb
__global__ __launch_bounds__(128) void k_prep(const float* __restrict__ Wq, const float* __restrict__ bq,
        const float* __restrict__ Wk, const float* __restrict__ bk,
        const float* __restrict__ Wv, const float* __restrict__ bv,
        const float* __restrict__ Wo, const float* __restrict__ bo, float* __restrict__ tc) {
    __shared__ float s_q[128], s_k[128], s_v[128];
    int t = threadIdx.x;
    float aq = 0, ak = 0, av = 0;
    for (int c = 0; c < 128; ++c) {
        aq += Wq[c * 128 + t]; ak += Wk[c * 128 + t]; av += Wv[c * 128 + t];
    }
    s_q[t] = aq; s_k[t] = ak; s_v[t] = av;
    tc[t] = aq; tc[128 + t] = ak; tc[256 + t] = av;
    __syncthreads();
    float pb = 0;
    for (int d = 0; d < 128; ++d) pb += bv[d] * Wo[d * 128 + t];
    tc[1440 + t] = pb + bo[t];
    for (int hh = 0; hh < 8; ++hh) {
        float p = 0;
        #pragma unroll
        for (int d = hh * 16; d < hh * 16 + 16; ++d) p += s_v[d] * Wo[d * 128 + t];
        tc[416 + hh * 128 + t] = p;
    }
    if (t < 8) {
        float A = 0, B = 0, C = 0, D = 0;
        #pragma unroll
        for (int d = t * 16; d < t * 16 + 16; ++d) {
            A += s_q[d] * s_k[d]; B += s_q[d] * bk[d];
            C += bq[d] * s_k[d];  D += bq[d] * bk[d];
        }
        tc[384 + t] = A; tc[392 + t] = B; tc[400 + t] = C; tc[408 + t] = D;
    }
}

// W1 [128][2048] fp32 -> W1T [2048][128] bf16
__global__ void k_w1t(const float* __restrict__ W1, u16* __restrict__ w1t) {
    int t = blockIdx.x * 256 + threadIdx.x;
    int f = t >> 7, c = t & 127;
    w1t[t] = f2bf(W1[c * 2048 + f]);
}
// W2 [2048][128] fp32 -> W2T [128][2048] bf16
__global__ void k_w2t(const float* __restrict__ W2, u16* __restrict__ w2t) {
    int t = blockIdx.x * 256 + threadIdx.x;
    int o = t >> 11, f = t & 2047;
    w2t[t] = f2bf(W2[f * 128 + o]);
}

// ---------------- attention (collapsed) + LN1 -> x1 (fp32, in d_out) ----------------
__global__ __launch_bounds__(256) void k_attn(const float* __restrict__ h3, const float* __restrict__ tc,
        const float* __restrict__ g1, const float* __restrict__ b1n, float* __restrict__ x1) {
    __shared__ float sh[32];
    __shared__ float ws_[8][32];
    int n = blockIdx.x, t = threadIdx.x;
    if (t < 32) sh[t] = h3[(size_t)n * 32 + t];
    __syncthreads();
    {   // w[hh,i] = sum_j softmax_j(coef*h_j) * h_j ;  coef = (h_i*A+C)/4
        int hh = t >> 5, i = t & 31;
        float A = tc[384 + hh], C = tc[400 + hh];
        float coef = (sh[i] * A + C) * 0.25f;
        float m = -1e30f;
        #pragma unroll
        for (int j = 0; j < 32; ++j) m = fmaxf(m, coef * sh[j]);
        float s = 0.f, wsum = 0.f;
        #pragma unroll
        for (int j = 0; j < 32; ++j) {
            float e = __expf(coef * sh[j] - m);
            s += e; wsum += e * sh[j];
        }
        ws_[hh][i] = wsum / s;
    }
    __syncthreads();
    int wave = t >> 6, lane = t & 63;
    float pb0 = tc[1440 + lane], pb1 = tc[1440 + lane + 64];
    float po0[8], po1[8];
    #pragma unroll
    for (int hh = 0; hh < 8; ++hh) {
        po0[hh] = tc[416 + hh * 128 + lane];
        po1[hh] = tc[416 + hh * 128 + lane + 64];
    }
    float ga = g1[lane], gb = g1[lane + 64], ba = b1n[lane], bb = b1n[lane + 64];
    for (int i = wave; i < 32; i += 4) {
        float y0 = sh[i] + pb0, y1 = sh[i] + pb1;
        #pragma unroll
        for (int hh = 0; hh < 8; ++hh) {
            float w = ws_[hh][i];
            y0 += w * po0[hh]; y1 += w * po1[hh];
        }
        float s1 = y0 + y1, s2 = y0 * y0 + y1 * y1;
        #pragma unroll
        for (int off = 1; off < 64; off <<= 1) {
            s1 += __shfl_xor(s1, off); s2 += __shfl_xor(s2, off);
        }
        float mu = s1 * (1.f / 128.f);
        float var = s2 * (1.f / 128.f) - mu * mu;
        float rs = rsqrtf(var + 1e-5f);
        size_t base = ((size_t)n * 32 + i) * 128;
        x1[base + lane]      = (y0 - mu) * rs * ga + ba;
        x1[base + lane + 64] = (y1 - mu) * rs * gb + bb;
    }
}

// ---------------- fused FFN + residual + LN2: R6 math, LDS-staged weights ----------------
// Math bit-identical to R10 (absmax 0.0156): same MFMA chains, same RNE conversions,
// bf16 residual (bf2f(f2bf(x1))). Weights staged global->LDS via global_load_lds,
// double-buffered in two STATIC buffers (wA/wB) so the compiler can disambiguate
// LDS-DMA writes from ds_reads of the other buffer. Pre-swizzled global source +
// XOR-swizzled reads (bank-balanced: 8 disjoint 4-bank groups).

// stage one 64-wide F-chunk: W1 16KB at [0), W2 16KB at [16384)
#define STAGE(buf, Fb) {                                                         \
    char* db_ = (char*)(buf);                                                    \
    _Pragma("unroll") for (int c1_ = 0; c1_ < 4; ++c1_) {                        \
        int f_ = c1_ * 16 + (t >> 4);                                            \
        int bo_ = ((t & 15) * 16) ^ ((f_ & 7) << 4);                             \
        GLD16(w1t + (size_t)((Fb) + f_) * 128 + (bo_ >> 1),                      \
              db_ + c1_ * 4096 + wave * 1024);                                   \
    }                                                                            \
    _Pragma("unroll") for (int c2_ = 0; c2_ < 4; ++c2_) {                        \
        int o_ = c2_ * 32 + (t >> 3);                                            \
        int bo_ = ((t & 7) * 16) ^ ((o_ & 7) << 4);                              \
        GLD16(w2t + (size_t)o_ * 2048 + (Fb) + (bo_ >> 1),                       \
              db_ + 16384 + c2_ * 4096 + wave * 1024);                           \
    } }

#define FCOMP(buf, Fb) {                                                         \
    const char* wb_ = (const char*)(buf);                                        \
    _Pragma("unroll") for (int cf_ = 0; cf_ < 4; ++cf_) {                        \
        bf16x8 w1f_[4];                                                          \
        _Pragma("unroll") for (int ks_ = 0; ks_ < 4; ++ks_)                      \
            w1f_[ks_] = *(const bf16x8*)(wb_ + (cf_ * 16 + li) * 256 +           \
                ((ks_ * 64 + g * 16) ^ ((li & 7) << 4)));                        \
        f32x4 a0_ = (f32x4){0.f, 0.f, 0.f, 0.f};                                 \
        f32x4 a1_ = (f32x4){0.f, 0.f, 0.f, 0.f};                                 \
        _Pragma("unroll") for (int ks_ = 0; ks_ < 4; ++ks_) {                    \
            a0_ = __builtin_amdgcn_mfma_f32_16x16x32_bf16(af[0][ks_], w1f_[ks_], a0_, 0, 0, 0); \
            a1_ = __builtin_amdgcn_mfma_f32_16x16x32_bf16(af[1][ks_], w1f_[ks_], a1_, 0, 0, 0); \
        }                                                                        \
        float bias_ = b1[(Fb) + cf_ * 16 + li];                                  \
        _Pragma("unroll") for (int r_ = 0; r_ < 4; ++r_) {                       \
            int row0_ = g * 4 + r_;                                              \
            int row1_ = 16 + g * 4 + r_;                                         \
            *(u16*)(hwb + ((row0_ * 128 + (cf_ * 16 + li) * 2) ^ ((row0_ & 7) << 4))) \
                = f2bf(fmaxf(a0_[r_] + bias_, 0.f));                             \
            *(u16*)(hwb + ((row1_ * 128 + (cf_ * 16 + li) * 2) ^ ((row1_ & 7) << 4))) \
                = f2bf(fmaxf(a1_[r_] + bias_, 0.f));                             \
        }                                                                        \
    }                                                                            \
    _Pragma("unroll") for (int k2_ = 0; k2_ < 2; ++k2_) {                        \
        bf16x8 a2_[2];                                                           \
        _Pragma("unroll") for (int rf_ = 0; rf_ < 2; ++rf_) {                    \
            int row_ = rf_ * 16 + li;                                            \
            a2_[rf_] = *(const bf16x8*)(hwb +                                    \
                ((row_ * 128 + (k2_ * 32 + g * 8) * 2) ^ ((row_ & 7) << 4)));    \
        }                                                                        \
        _Pragma("unroll") for (int c2_ = 0; c2_ < 8; ++c2_) {                    \
            bf16x8 w2f_ = *(const bf16x8*)(wb_ + 16384 + (c2_ * 16 + li) * 128 + \
                ((k2_ * 64 + g * 16) ^ ((li & 7) << 4)));                        \
            acc2[0][c2_] = __builtin_amdgcn_mfma_f32_16x16x32_bf16(a2_[0], w2f_, acc2[0][c2_], 0, 0, 0); \
            acc2[1][c2_] = __builtin_amdgcn_mfma_f32_16x16x32_bf16(a2_[1], w2f_, acc2[1][c2_], 0, 0, 0); \
        }                                                                        \
    } }

__global__ __launch_bounds__(256, 2) void k_ffn(const float* x1f, const u16* __restrict__ w1t,
        const u16* __restrict__ w2t, const float* __restrict__ b1, const float* __restrict__ b2,
        const float* __restrict__ g2, const float* __restrict__ bt2, float* out) {
    __shared__ u16 wA[16384];           // 32KB: W1 chunk + W2 chunk (buffer A)
    __shared__ u16 wB[16384];           // 32KB: buffer B
    __shared__ u16 hid[4][32 * 64];     // per-wave hidden scratch, swizzled
    int t = threadIdx.x, wave = t >> 6, lane = t & 63;
    int g = lane >> 4, li = lane & 15;
    size_t rowbase = (size_t)blockIdx.x * 128;
    char* hwb = (char*)&hid[wave][0];

    STAGE(wA, 0);

    // A(x1) fragments from global fp32, RNE-packed (bit-identical to R10's LDS path):
    // row = wave*32 + rf*16 + li ; k = ks*32 + g*8 + j
    bf16x8 af[2][4];
    #pragma unroll
    for (int rf = 0; rf < 2; ++rf)
    #pragma unroll
    for (int ks = 0; ks < 4; ++ks) {
        const float* p = x1f + (rowbase + wave * 32 + rf * 16 + li) * 128 + ks * 32 + g * 8;
        float4 v0 = *(const float4*)(p);
        float4 v1 = *(const float4*)(p + 4);
        u32x4 q = { pk2bf(v0.x, v0.y), pk2bf(v0.z, v0.w),
                    pk2bf(v1.x, v1.y), pk2bf(v1.z, v1.w) };
        af[rf][ks] = __builtin_bit_cast(bf16x8, q);
    }

    f32x4 acc2[2][8];
    #pragma unroll
    for (int a = 0; a < 2; ++a)
    #pragma unroll
    for (int b = 0; b < 8; ++b) acc2[a][b] = (f32x4){0.f, 0.f, 0.f, 0.f};

    __syncthreads();                    // wA staged

    for (int F = 0; F < FFD; F += 128) {
        STAGE(wB, F + 64);              // always valid: F+64 <= 1984
        FCOMP(wA, F);
        __syncthreads();                // wB ready; all reads of wA done
        if (F + 128 < FFD) STAGE(wA, F + 128);
        FCOMP(wB, F + 64);
        __syncthreads();
    }

    // epilogue (R10 math): residual = bf16(x1) via f2bf->bf2f of global value
    #pragma unroll
    for (int rf = 0; rf < 2; ++rf)
    #pragma unroll
    for (int r = 0; r < 4; ++r) {
        int lrow = wave * 32 + rf * 16 + g * 4 + r;
        size_t grow = rowbase + lrow;
        float vals[8], s1 = 0.f, s2 = 0.f;
        #pragma unroll
        for (int cf2 = 0; cf2 < 8; ++cf2) {
            int col = cf2 * 16 + li;
            float xv = bf2f(f2bf(x1f[grow * 128 + col]));
            float y = xv + acc2[rf][cf2][r] + b2[col];
            vals[cf2] = y; s1 += y; s2 += y * y;
        }
        #pragma unroll
        for (int m = 1; m < 16; m <<= 1) {
            s1 += __shfl_xor(s1, m); s2 += __shfl_xor(s2, m);
        }
        float mu = s1 * (1.f / 128.f);
        float var = s2 * (1.f / 128.f) - mu * mu;
        float rs = rsqrtf(var + 1e-5f);
        #pragma unroll
        for (int cf2 = 0; cf2 < 8; ++cf2) {
            int col = cf2 * 16 + li;
            out[grow * 128 + col] = (vals[cf2] - mu) * rs * g2[col] + bt2[col];
        }
    }
}

// ---------------- launch ----------------
extern "C" void kernel_launch(void* const* d_in, const int* in_sizes, int n_in,
                              void* d_out, int out_size, void* d_ws, size_t ws_size,
                              hipStream_t stream) {
    const float* x   = (const float*)d_in[0];
    const int*   ei  = (const int*)d_in[1];
    const float *Wg1 = (const float*)d_in[2],  *bg1 = (const float*)d_in[3];
    const float *Wg2 = (const float*)d_in[4],  *bg2 = (const float*)d_in[5];
    const float *Wg3 = (const float*)d_in[6],  *bg3 = (const float*)d_in[7];
    const float *Wq  = (const float*)d_in[8],  *bq  = (const float*)d_in[9];
    const float *Wk  = (const float*)d_in[10], *bk  = (const float*)d_in[11];
    const float *Wv  = (const float*)d_in[12], *bv  = (const float*)d_in[13];
    const float *Wo  = (const float*)d_in[14], *bo  = (const float*)d_in[15];
    const float *g1  = (const float*)d_in[16], *b1n = (const float*)d_in[17];
    const float *W1  = (const float*)d_in[18], *b1  = (const float*)d_in[19];
    const float *W2  = (const float*)d_in[20], *b2  = (const float*)d_in[21];
    const float *g2  = (const float*)d_in[22], *bt2 = (const float*)d_in[23];

    char* ws = (char*)d_ws;
    int*   flag = (int*)(ws + 0);
    int*   cnt  = (int*)(ws + 4096);
    int*   rp   = (int*)(ws + 20480);
    int*   cur  = (int*)(ws + 40960);
    float* dinv = (float*)(ws + 57344);
    float* ms   = (float*)(ws + 73728);      // 2 MB
    int*   es   = (int*)(ws + 2170880);      // 512 KB
    float* hA   = (float*)(ws + 2695168);    // 2 MB (h1, later h3)
    float* hB   = (float*)(ws + 4792320);    // 2 MB (h2)
    float* tc   = (float*)(ws + 6889472);
    u16*   w1t  = (u16*)(ws + 6897664);      // 512 KB
    u16*   w2t  = (u16*)(ws + 7421952);      // 512 KB
    float* x1   = (float*)d_out;             // fp32 x1 staged in d_out; FFN in-place
    float* out  = (float*)d_out;

    k_detect<<<1, 64, 0, stream>>>(ei, flag);
    hipMemsetAsync(cnt, 0, 16384, stream);
    k_degi<<<512, 256, 0, stream>>>(ei, flag, cnt);
    k_dinv<<<16, 256, 0, stream>>>(cnt, dinv);
    k_scan<<<1, 1024, 0, stream>>>(cnt, rp, cur);
    k_bucket<<<512, 256, 0, stream>>>(ei, flag, cur, es);

    // GCN layer 1
    k_gcn_mm128<<<2048, 256, 0, stream>>>(x, Wg1, dinv, ms);
    k_gath128<<<1024, 256, 0, stream>>>(es, rp, ms, dinv, bg1, hA);
    // GCN layer 2
    k_gcn_mm128<<<2048, 256, 0, stream>>>(hA, Wg2, dinv, ms);
    k_gath128<<<1024, 256, 0, stream>>>(es, rp, ms, dinv, bg2, hB);
    // GCN layer 3
    k_gcn_mm32<<<512, 256, 0, stream>>>(hB, Wg3, dinv, ms);
    k_gath32<<<512, 256, 0, stream>>>(es, rp, ms, dinv, bg3, hA);

    // transformer precompute
    k_prep<<<1, 128, 0, stream>>>(Wq, bq, Wk, bk, Wv, bv, Wo, bo, tc);
    k_w1t<<<1024, 256, 0, stream>>>(W1, w1t);
    k_w2t<<<1024, 256, 0, stream>>>(W2, w2t);

    // attention + LN1 -> x1 (fp32, into d_out)
    k_attn<<<4096, 256, 0, stream>>>(hA, tc, g1, b1n, x1);

    // FFN + residual + LN2 -> out (fp32, in-place on d_out)
    k_ffn<<<1024, 256, 0, stream>>>(x1, w1t, w2t, b1, b2, g2, bt2, out);
}